// Round 1
// baseline (2923.851 us; speedup 1.0000x reference)
//
#include <hip/hip_runtime.h>
#include <math.h>

#define EMBED 256
#define HEADS 8
#define LEVELS 4
#define POINTS 4
#define FFNDIM 1024
#define HD 32

static __device__ __forceinline__ float4 ld4(const float* p) {
    return *reinterpret_cast<const float4*>(p);
}
static __device__ __forceinline__ void st4(float* p, float4 v) {
    *reinterpret_cast<float4*>(p) = v;
}

// ---------------------------------------------------------------------------
// Generic GEMM: C(M,256) = A(M,256) @ W(256,256) + bias
// Tile: 16 rows x 256 cols, K staged in chunks of 32 via LDS. 256 threads,
// each owns a 4x4 micro-tile. A-reads are wave-uniform ds_read_b128
// broadcasts; W-reads contiguous b128 -> VALU-bound (~16 FMA : 2 b128).
// ---------------------------------------------------------------------------
__global__ __launch_bounds__(256)
void k_gemm256(const float* __restrict__ A, const float* __restrict__ W,
               const float* __restrict__ bias, float* __restrict__ C, int M)
{
    __shared__ float as[16 * 256];
    __shared__ float ws[32 * 256];
    const int tid = threadIdx.x;
    const int m0 = blockIdx.x * 16;
    const int rows = M - m0;  // valid rows in this tile (may exceed 16)

    // Stage A tile (16x256) coalesced via float4; zero-pad OOB rows.
    for (int j = tid; j < 16 * 64; j += 256) {
        int r = j >> 6;
        float4 v = make_float4(0.f, 0.f, 0.f, 0.f);
        if (r < rows) v = ld4(A + (size_t)(m0 + r) * 256 + ((j & 63) << 2));
        st4(as + (j << 2), v);
    }

    const int r0 = (tid >> 6) << 2;  // wave-uniform row group
    const int c0 = (tid & 63) << 2;
    float acc[4][4] = {};

    for (int kc = 0; kc < 8; ++kc) {
        __syncthreads();
        for (int j = tid; j < 32 * 64; j += 256) {
            int kk = j >> 6, c4 = (j & 63) << 2;
            st4(ws + kk * 256 + c4, ld4(W + (size_t)(kc * 32 + kk) * 256 + c4));
        }
        __syncthreads();
        #pragma unroll
        for (int k4 = 0; k4 < 8; ++k4) {
            float a[4][4], w[4][4];
            #pragma unroll
            for (int i = 0; i < 4; ++i) {
                float4 t = ld4(&as[(r0 + i) * 256 + kc * 32 + k4 * 4]);
                a[i][0] = t.x; a[i][1] = t.y; a[i][2] = t.z; a[i][3] = t.w;
            }
            #pragma unroll
            for (int kk = 0; kk < 4; ++kk) {
                float4 t = ld4(&ws[(k4 * 4 + kk) * 256 + c0]);
                w[kk][0] = t.x; w[kk][1] = t.y; w[kk][2] = t.z; w[kk][3] = t.w;
            }
            #pragma unroll
            for (int kk = 0; kk < 4; ++kk)
                #pragma unroll
                for (int i = 0; i < 4; ++i)
                    #pragma unroll
                    for (int j = 0; j < 4; ++j)
                        acc[i][j] += a[i][kk] * w[kk][j];
        }
    }

    float4 bv = ld4(bias + c0);
    #pragma unroll
    for (int i = 0; i < 4; ++i) {
        int row = r0 + i;
        if (row < rows) {
            float4 o = make_float4(acc[i][0] + bv.x, acc[i][1] + bv.y,
                                   acc[i][2] + bv.z, acc[i][3] + bv.w);
            st4(C + (size_t)(m0 + row) * 256 + c0, o);
        }
    }
}

// ---------------------------------------------------------------------------
// Attention-logit GEMM (256->128) with fused per-head softmax over 16 cols.
// Tile: 32 rows x 128 cols; cluster of 4 threads covers one head's 16 cols.
// ---------------------------------------------------------------------------
__global__ __launch_bounds__(256)
void k_att(const float* __restrict__ A, const float* __restrict__ W,
           const float* __restrict__ bias, float* __restrict__ C, int M)
{
    __shared__ float as[32 * 256];
    __shared__ float ws[32 * 128];
    const int tid = threadIdx.x;
    const int m0 = blockIdx.x * 32;
    const int rows = M - m0;

    for (int j = tid; j < 32 * 64; j += 256) {
        int r = j >> 6;
        float4 v = make_float4(0.f, 0.f, 0.f, 0.f);
        if (r < rows) v = ld4(A + (size_t)(m0 + r) * 256 + ((j & 63) << 2));
        st4(as + (j << 2), v);
    }

    const int r0 = (tid >> 5) << 2;  // 8 row groups of 4
    const int c0 = (tid & 31) << 2;  // 32 col groups of 4
    float acc[4][4] = {};

    for (int kc = 0; kc < 8; ++kc) {
        __syncthreads();
        for (int j = tid; j < 32 * 32; j += 256) {
            int kk = j >> 5, c4 = (j & 31) << 2;
            st4(ws + kk * 128 + c4, ld4(W + (size_t)(kc * 32 + kk) * 128 + c4));
        }
        __syncthreads();
        #pragma unroll
        for (int k4 = 0; k4 < 8; ++k4) {
            float a[4][4], w[4][4];
            #pragma unroll
            for (int i = 0; i < 4; ++i) {
                float4 t = ld4(&as[(r0 + i) * 256 + kc * 32 + k4 * 4]);
                a[i][0] = t.x; a[i][1] = t.y; a[i][2] = t.z; a[i][3] = t.w;
            }
            #pragma unroll
            for (int kk = 0; kk < 4; ++kk) {
                float4 t = ld4(&ws[(k4 * 4 + kk) * 128 + c0]);
                w[kk][0] = t.x; w[kk][1] = t.y; w[kk][2] = t.z; w[kk][3] = t.w;
            }
            #pragma unroll
            for (int kk = 0; kk < 4; ++kk)
                #pragma unroll
                for (int i = 0; i < 4; ++i)
                    #pragma unroll
                    for (int j = 0; j < 4; ++j)
                        acc[i][j] += a[i][kk] * w[kk][j];
        }
    }

    float4 bv = ld4(bias + c0);
    #pragma unroll
    for (int i = 0; i < 4; ++i) {
        acc[i][0] += bv.x; acc[i][1] += bv.y; acc[i][2] += bv.z; acc[i][3] += bv.w;
    }
    // softmax over each 16-col head group; partners = 4 consecutive lanes
    #pragma unroll
    for (int i = 0; i < 4; ++i) {
        float m = fmaxf(fmaxf(acc[i][0], acc[i][1]), fmaxf(acc[i][2], acc[i][3]));
        m = fmaxf(m, __shfl_xor(m, 1));
        m = fmaxf(m, __shfl_xor(m, 2));
        float e[4], s = 0.f;
        #pragma unroll
        for (int j = 0; j < 4; ++j) { e[j] = __expf(acc[i][j] - m); s += e[j]; }
        s += __shfl_xor(s, 1);
        s += __shfl_xor(s, 2);
        float inv = 1.f / s;
        #pragma unroll
        for (int j = 0; j < 4; ++j) acc[i][j] = e[j] * inv;
    }
    #pragma unroll
    for (int i = 0; i < 4; ++i) {
        int row = r0 + i;
        if (row < rows)
            st4(C + (size_t)(m0 + row) * 128 + c0,
                make_float4(acc[i][0], acc[i][1], acc[i][2], acc[i][3]));
    }
}

// ---------------------------------------------------------------------------
// Deformable sampling core. 32 lanes per (token, head), one lane per channel.
// value gathers coalesce to 128B per 32-lane group. loc computed on the fly.
// ---------------------------------------------------------------------------
__global__ __launch_bounds__(256)
void k_sample(const float* __restrict__ value,  // (B*nk, 8, 32)
              const float* __restrict__ offr,   // (M, 256) raw offsets
              const float* __restrict__ attw,   // (M, 128) softmaxed
              const float* __restrict__ ref,    // (M, 4, 2)
              const int* __restrict__ shapes,   // (4, 2) [H, W]
              const int* __restrict__ lsi,      // (4)
              float* __restrict__ core,         // (M, 256)
              int M)
{
    const int tid = threadIdx.x;
    const int pair = blockIdx.x * 8 + (tid >> 5);
    const int d = tid & 31;
    const int tok = pair >> 3, h = pair & 7;
    if (tok >= M) return;

    const int nk = lsi[3] + shapes[6] * shapes[7];
    const int b = tok / nk;  // nq == nk
    const float* vb = value + (size_t)b * nk * 256;

    float acc = 0.f;
    #pragma unroll
    for (int l = 0; l < LEVELS; ++l) {
        const int Hl = shapes[l * 2], Wl = shapes[l * 2 + 1];
        const float rx = ref[(size_t)tok * 8 + l * 2 + 0];
        const float ry = ref[(size_t)tok * 8 + l * 2 + 1];
        const float* vl = vb + (size_t)lsi[l] * 256 + h * 32 + d;
        #pragma unroll
        for (int p = 0; p < POINTS; ++p) {
            const int oi = tok * 256 + ((h * 4 + l) * 4 + p) * 2;
            const float ox = offr[oi], oy = offr[oi + 1];
            const float aw = attw[tok * 128 + h * 16 + l * 4 + p];
            const float x = (rx + ox / (float)Wl) * (float)Wl - 0.5f;
            const float y = (ry + oy / (float)Hl) * (float)Hl - 0.5f;
            const float x0f = floorf(x), y0f = floorf(y);
            const float fx = x - x0f, fy = y - y0f;
            const int x0 = (int)x0f, y0 = (int)y0f;
            #pragma unroll
            for (int t = 0; t < 4; ++t) {
                const int dx = t & 1, dy = t >> 1;
                const int xi = x0 + dx, yi = y0 + dy;
                const bool valid = (xi >= 0) & (xi < Wl) & (yi >= 0) & (yi < Hl);
                const float w = (dx ? fx : 1.f - fx) * (dy ? fy : 1.f - fy);
                const int xc = min(max(xi, 0), Wl - 1);
                const int yc = min(max(yi, 0), Hl - 1);
                const float v = vl[(size_t)(yc * Wl + xc) * 256];
                acc += valid ? (w * aw) * v : 0.f;
            }
        }
    }
    core[(size_t)tok * 256 + h * 32 + d] = acc;
}

// ---------------------------------------------------------------------------
// Out-projection + residual + LayerNorm1 fused: x = LN(src + core@w_out + b)
// ---------------------------------------------------------------------------
__global__ __launch_bounds__(256)
void k_outproj_ln(const float* __restrict__ A, const float* __restrict__ W,
                  const float* __restrict__ bias, const float* __restrict__ src,
                  const float* __restrict__ g1, const float* __restrict__ bt1,
                  float* __restrict__ X, int M)
{
    __shared__ float as[16 * 256];
    __shared__ float ws[32 * 256];  // reused as LN value buffer afterwards
    __shared__ float mean_s[16], rstd_s[16];
    const int tid = threadIdx.x;
    const int m0 = blockIdx.x * 16;
    const int rows = M - m0;

    for (int j = tid; j < 16 * 64; j += 256) {
        int r = j >> 6;
        float4 v = make_float4(0.f, 0.f, 0.f, 0.f);
        if (r < rows) v = ld4(A + (size_t)(m0 + r) * 256 + ((j & 63) << 2));
        st4(as + (j << 2), v);
    }

    const int r0 = (tid >> 6) << 2;
    const int c0 = (tid & 63) << 2;
    float acc[4][4] = {};

    for (int kc = 0; kc < 8; ++kc) {
        __syncthreads();
        for (int j = tid; j < 32 * 64; j += 256) {
            int kk = j >> 6, c4 = (j & 63) << 2;
            st4(ws + kk * 256 + c4, ld4(W + (size_t)(kc * 32 + kk) * 256 + c4));
        }
        __syncthreads();
        #pragma unroll
        for (int k4 = 0; k4 < 8; ++k4) {
            float a[4][4], w[4][4];
            #pragma unroll
            for (int i = 0; i < 4; ++i) {
                float4 t = ld4(&as[(r0 + i) * 256 + kc * 32 + k4 * 4]);
                a[i][0] = t.x; a[i][1] = t.y; a[i][2] = t.z; a[i][3] = t.w;
            }
            #pragma unroll
            for (int kk = 0; kk < 4; ++kk) {
                float4 t = ld4(&ws[(k4 * 4 + kk) * 256 + c0]);
                w[kk][0] = t.x; w[kk][1] = t.y; w[kk][2] = t.z; w[kk][3] = t.w;
            }
            #pragma unroll
            for (int kk = 0; kk < 4; ++kk)
                #pragma unroll
                for (int i = 0; i < 4; ++i)
                    #pragma unroll
                    for (int j = 0; j < 4; ++j)
                        acc[i][j] += a[i][kk] * w[kk][j];
        }
    }

    __syncthreads();  // done reading ws; reuse as vals[16][256]
    float4 bv = ld4(bias + c0);
    float v[4][4];
    #pragma unroll
    for (int i = 0; i < 4; ++i) {
        int row = r0 + i;
        float4 sv = make_float4(0.f, 0.f, 0.f, 0.f);
        if (row < rows) sv = ld4(src + (size_t)(m0 + row) * 256 + c0);
        v[i][0] = acc[i][0] + bv.x + sv.x;
        v[i][1] = acc[i][1] + bv.y + sv.y;
        v[i][2] = acc[i][2] + bv.z + sv.z;
        v[i][3] = acc[i][3] + bv.w + sv.w;
        st4(&ws[row * 256 + c0], make_float4(v[i][0], v[i][1], v[i][2], v[i][3]));
    }
    __syncthreads();

    const int rr = tid >> 4, g = tid & 15;
    float s1 = 0.f, s2 = 0.f;
    #pragma unroll
    for (int i = 0; i < 16; ++i) {
        float t = ws[rr * 256 + g + i * 16];
        s1 += t; s2 += t * t;
    }
    #pragma unroll
    for (int m = 1; m < 16; m <<= 1) {
        s1 += __shfl_xor(s1, m);
        s2 += __shfl_xor(s2, m);
    }
    if (g == 0) {
        float mu = s1 * (1.f / 256.f);
        mean_s[rr] = mu;
        rstd_s[rr] = rsqrtf(fmaxf(s2 * (1.f / 256.f) - mu * mu, 0.f) + 1e-5f);
    }
    __syncthreads();

    float4 gv = ld4(g1 + c0), btv = ld4(bt1 + c0);
    #pragma unroll
    for (int i = 0; i < 4; ++i) {
        int row = r0 + i;
        if (row < rows) {
            float mu = mean_s[row], rs = rstd_s[row];
            float4 o = make_float4((v[i][0] - mu) * rs * gv.x + btv.x,
                                   (v[i][1] - mu) * rs * gv.y + btv.y,
                                   (v[i][2] - mu) * rs * gv.z + btv.z,
                                   (v[i][3] - mu) * rs * gv.w + btv.w);
            st4(X + (size_t)(m0 + row) * 256 + c0, o);
        }
    }
}

// ---------------------------------------------------------------------------
// Fused FFN + residual + LayerNorm2: out = LN(x + relu(x@w1+b1)@w2 + b2)
// LDS: x-tile 16KB + h-tile 64KB + W-stage 32KB = 112KB (1 block/CU).
// ---------------------------------------------------------------------------
__global__ __launch_bounds__(256)
void k_ffn_ln(const float* __restrict__ X, const float* __restrict__ W1,
              const float* __restrict__ B1, const float* __restrict__ W2,
              const float* __restrict__ B2, const float* __restrict__ G2,
              const float* __restrict__ BT2, float* __restrict__ OUT, int M)
{
    __shared__ float xs[16 * 256];
    __shared__ float hs[16 * 1024];
    __shared__ float ws[32 * 256];
    __shared__ float mean_s[16], rstd_s[16];
    const int tid = threadIdx.x;
    const int m0 = blockIdx.x * 16;
    const int rows = M - m0;

    for (int j = tid; j < 16 * 64; j += 256) {
        int r = j >> 6;
        float4 v = make_float4(0.f, 0.f, 0.f, 0.f);
        if (r < rows) v = ld4(X + (size_t)(m0 + r) * 256 + ((j & 63) << 2));
        st4(xs + (j << 2), v);
    }

    const int r0 = (tid >> 6) << 2;
    const int c0 = (tid & 63) << 2;

    // ---- GEMM1: h = relu(x @ W1 + b1), 1024 cols in 4 chunks of 256 ----
    for (int cc = 0; cc < 4; ++cc) {
        float acc[4][4] = {};
        for (int kc = 0; kc < 8; ++kc) {
            __syncthreads();
            for (int j = tid; j < 32 * 64; j += 256) {
                int kk = j >> 6, c4 = (j & 63) << 2;
                st4(ws + kk * 256 + c4,
                    ld4(W1 + (size_t)(kc * 32 + kk) * 1024 + cc * 256 + c4));
            }
            __syncthreads();
            #pragma unroll
            for (int k4 = 0; k4 < 8; ++k4) {
                float a[4][4], w[4][4];
                #pragma unroll
                for (int i = 0; i < 4; ++i) {
                    float4 t = ld4(&xs[(r0 + i) * 256 + kc * 32 + k4 * 4]);
                    a[i][0] = t.x; a[i][1] = t.y; a[i][2] = t.z; a[i][3] = t.w;
                }
                #pragma unroll
                for (int kk = 0; kk < 4; ++kk) {
                    float4 t = ld4(&ws[(k4 * 4 + kk) * 256 + c0]);
                    w[kk][0] = t.x; w[kk][1] = t.y; w[kk][2] = t.z; w[kk][3] = t.w;
                }
                #pragma unroll
                for (int kk = 0; kk < 4; ++kk)
                    #pragma unroll
                    for (int i = 0; i < 4; ++i)
                        #pragma unroll
                        for (int j = 0; j < 4; ++j)
                            acc[i][j] += a[i][kk] * w[kk][j];
            }
        }
        float4 bv = ld4(B1 + cc * 256 + c0);
        #pragma unroll
        for (int i = 0; i < 4; ++i) {
            float4 o = make_float4(fmaxf(acc[i][0] + bv.x, 0.f),
                                   fmaxf(acc[i][1] + bv.y, 0.f),
                                   fmaxf(acc[i][2] + bv.z, 0.f),
                                   fmaxf(acc[i][3] + bv.w, 0.f));
            st4(&hs[(r0 + i) * 1024 + cc * 256 + c0], o);
        }
    }

    // ---- GEMM2: y = h @ W2 + b2, K=1024 in 32 chunks ----
    float acc2[4][4] = {};
    for (int kc = 0; kc < 32; ++kc) {
        __syncthreads();  // first iteration also makes hs visible
        for (int j = tid; j < 32 * 64; j += 256) {
            int kk = j >> 6, c4 = (j & 63) << 2;
            st4(ws + kk * 256 + c4,
                ld4(W2 + (size_t)(kc * 32 + kk) * 256 + c4));
        }
        __syncthreads();
        #pragma unroll
        for (int k4 = 0; k4 < 8; ++k4) {
            float a[4][4], w[4][4];
            #pragma unroll
            for (int i = 0; i < 4; ++i) {
                float4 t = ld4(&hs[(r0 + i) * 1024 + kc * 32 + k4 * 4]);
                a[i][0] = t.x; a[i][1] = t.y; a[i][2] = t.z; a[i][3] = t.w;
            }
            #pragma unroll
            for (int kk = 0; kk < 4; ++kk) {
                float4 t = ld4(&ws[(k4 * 4 + kk) * 256 + c0]);
                w[kk][0] = t.x; w[kk][1] = t.y; w[kk][2] = t.z; w[kk][3] = t.w;
            }
            #pragma unroll
            for (int kk = 0; kk < 4; ++kk)
                #pragma unroll
                for (int i = 0; i < 4; ++i)
                    #pragma unroll
                    for (int j = 0; j < 4; ++j)
                        acc2[i][j] += a[i][kk] * w[kk][j];
        }
    }

    __syncthreads();  // done with ws; reuse as vals[16][256]
    float4 bv = ld4(B2 + c0);
    float v[4][4];
    #pragma unroll
    for (int i = 0; i < 4; ++i) {
        int row = r0 + i;
        float4 xv = ld4(&xs[row * 256 + c0]);
        v[i][0] = acc2[i][0] + bv.x + xv.x;
        v[i][1] = acc2[i][1] + bv.y + xv.y;
        v[i][2] = acc2[i][2] + bv.z + xv.z;
        v[i][3] = acc2[i][3] + bv.w + xv.w;
        st4(&ws[row * 256 + c0], make_float4(v[i][0], v[i][1], v[i][2], v[i][3]));
    }
    __syncthreads();

    const int rr = tid >> 4, g = tid & 15;
    float s1 = 0.f, s2 = 0.f;
    #pragma unroll
    for (int i = 0; i < 16; ++i) {
        float t = ws[rr * 256 + g + i * 16];
        s1 += t; s2 += t * t;
    }
    #pragma unroll
    for (int m = 1; m < 16; m <<= 1) {
        s1 += __shfl_xor(s1, m);
        s2 += __shfl_xor(s2, m);
    }
    if (g == 0) {
        float mu = s1 * (1.f / 256.f);
        mean_s[rr] = mu;
        rstd_s[rr] = rsqrtf(fmaxf(s2 * (1.f / 256.f) - mu * mu, 0.f) + 1e-5f);
    }
    __syncthreads();

    float4 gv = ld4(G2 + c0), btv = ld4(BT2 + c0);
    #pragma unroll
    for (int i = 0; i < 4; ++i) {
        int row = r0 + i;
        if (row < rows) {
            float mu = mean_s[row], rs = rstd_s[row];
            float4 o = make_float4((v[i][0] - mu) * rs * gv.x + btv.x,
                                   (v[i][1] - mu) * rs * gv.y + btv.y,
                                   (v[i][2] - mu) * rs * gv.z + btv.z,
                                   (v[i][3] - mu) * rs * gv.w + btv.w);
            st4(OUT + (size_t)(m0 + row) * 256 + c0, o);
        }
    }
}

// ---------------------------------------------------------------------------
extern "C" void kernel_launch(void* const* d_in, const int* in_sizes, int n_in,
                              void* d_out, int out_size, void* d_ws, size_t ws_size,
                              hipStream_t stream) {
    const float* src    = (const float*)d_in[0];
    const float* ref    = (const float*)d_in[1];
    const int*   shapes = (const int*)d_in[2];
    const int*   lsi    = (const int*)d_in[3];
    const float* w_off  = (const float*)d_in[4];
    const float* b_off  = (const float*)d_in[5];
    const float* w_att  = (const float*)d_in[6];
    const float* b_att  = (const float*)d_in[7];
    const float* w_val  = (const float*)d_in[8];
    const float* b_val  = (const float*)d_in[9];
    const float* w_out  = (const float*)d_in[10];
    const float* b_out  = (const float*)d_in[11];
    const float* g1     = (const float*)d_in[12];
    const float* bt1    = (const float*)d_in[13];
    const float* w1     = (const float*)d_in[14];
    const float* b1     = (const float*)d_in[15];
    const float* w2     = (const float*)d_in[16];
    const float* b2     = (const float*)d_in[17];
    const float* g2     = (const float*)d_in[18];
    const float* bt2    = (const float*)d_in[19];

    const int M = in_sizes[0] / EMBED;  // B*nq = 49130
    float* wsf = (float*)d_ws;
    const size_t MS = (size_t)M * 256;
    float* value = wsf;                         // (M,256)
    float* offr  = wsf + MS;                    // (M,256)
    float* attw  = wsf + 2 * MS;                // (M,128)
    float* core  = wsf + 2 * MS + (size_t)M * 128;  // (M,256)
    float* xbuf  = wsf;                         // reuse value region after sampling

    const int gb16 = (M + 15) / 16;
    const int gb32 = (M + 31) / 32;

    k_gemm256<<<gb16, 256, 0, stream>>>(src, w_val, b_val, value, M);
    k_gemm256<<<gb16, 256, 0, stream>>>(src, w_off, b_off, offr, M);
    k_att<<<gb32, 256, 0, stream>>>(src, w_att, b_att, attw, M);
    k_sample<<<M, 256, 0, stream>>>(value, offr, attw, ref, shapes, lsi, core, M);
    k_outproj_ln<<<gb16, 256, 0, stream>>>(core, w_out, b_out, src, g1, bt1, xbuf, M);
    k_ffn_ln<<<gb16, 256, 0, stream>>>(xbuf, w1, b1, w2, b2, g2, bt2,
                                       (float*)d_out, M);
}

// Round 2
// 1137.311 us; speedup vs baseline: 2.5708x; 2.5708x over previous
//
#include <hip/hip_runtime.h>
#include <math.h>

#define EMBED 256
#define HEADS 8
#define LEVELS 4
#define POINTS 4
#define FFNDIM 1024

typedef float f32x4 __attribute__((ext_vector_type(4)));
typedef __bf16 bf16x8 __attribute__((ext_vector_type(8)));

static __device__ __forceinline__ float4 ld4f(const float* p) {
    return *reinterpret_cast<const float4*>(p);
}
static __device__ __forceinline__ unsigned short f2bf(float f) {
    unsigned int u = __float_as_uint(f);
    unsigned int r = (u + 0x7fffu + ((u >> 16) & 1u)) >> 16;
    return (unsigned short)r;
}
static __device__ __forceinline__ float bf2f(unsigned short u) {
    return __uint_as_float((unsigned int)u << 16);
}

// ---------------------------------------------------------------------------
// fp32 -> bf16 (RNE) elementwise, vectorized
// ---------------------------------------------------------------------------
__global__ __launch_bounds__(256)
void k_cvt_src(const float* __restrict__ src, unsigned short* __restrict__ dst, int n)
{
    int i = (blockIdx.x * 256 + threadIdx.x) * 4;
    const int stride = gridDim.x * 1024;
    for (; i < n; i += stride) {
        float4 v = ld4f(src + i);
        ushort4 o;
        o.x = f2bf(v.x); o.y = f2bf(v.y); o.z = f2bf(v.z); o.w = f2bf(v.w);
        *reinterpret_cast<ushort4*>(dst + i) = o;
    }
}

// ---------------------------------------------------------------------------
// Weight transpose + convert: Wt[n][k] = bf16(W[k][n]) for all weights.
// Segments: wcat(640x256)=163840 | wout(256x256)=65536 | w1t(1024x256)=262144
//           | w2t(256x1024)=262144   (total 753664)
// ---------------------------------------------------------------------------
__global__ __launch_bounds__(256)
void k_cvt_w(const float* __restrict__ wv, const float* __restrict__ wo,
             const float* __restrict__ wa, const float* __restrict__ wout,
             const float* __restrict__ w1, const float* __restrict__ w2,
             unsigned short* __restrict__ wcat, unsigned short* __restrict__ woutt,
             unsigned short* __restrict__ w1t, unsigned short* __restrict__ w2t)
{
    const int total = 163840 + 65536 + 262144 + 262144;
    for (int gid = blockIdx.x * 256 + threadIdx.x; gid < total; gid += gridDim.x * 256) {
        int local = gid;
        float f; unsigned short* dst;
        if (local < 163840) {                       // wcat_t [640][256]
            int n = local >> 8, k = local & 255;
            if (n < 256)      f = wv[k * 256 + n];
            else if (n < 512) f = wo[k * 256 + (n - 256)];
            else              f = wa[k * 128 + (n - 512)];
            dst = wcat + local;
        } else if ((local -= 163840) < 65536) {     // wout_t [256][256]
            int n = local >> 8, k = local & 255;
            f = wout[k * 256 + n];
            dst = woutt + local;
        } else if ((local -= 65536) < 262144) {     // w1_t [1024][256]
            int n = local >> 8, k = local & 255;
            f = w1[k * 1024 + n];
            dst = w1t + local;
        } else {                                    // w2_t [256][1024]
            local -= 262144;
            int n = local >> 10, k = local & 1023;
            f = w2[k * 256 + n];
            dst = w2t + local;
        }
        *dst = f2bf(f);
    }
}

// ---------------------------------------------------------------------------
// Projection GEMM: [value|off|att](M,640) = src_bf(M,256) @ wcat_t^T + bias
// BM=128, BN=256, BK=64, 512 threads = 8 waves (2 M x 4 N), 16x16x32 MFMA.
// grid.y: 0=value(bf16 out), 1=off(bf16 out), 2=att(softmax16 -> bf16 out).
// LDS tiles padded (+8 bf16) -> 2-way read aliasing only.
// ---------------------------------------------------------------------------
__global__ __launch_bounds__(512)
void k_proj(const unsigned short* __restrict__ A, const unsigned short* __restrict__ Wt,
            const float* __restrict__ b_val, const float* __restrict__ b_off,
            const float* __restrict__ b_att,
            unsigned short* __restrict__ value, unsigned short* __restrict__ offr,
            unsigned short* __restrict__ attw, int M)
{
    __shared__ unsigned short a_s[128 * 72];
    __shared__ unsigned short w_s[256 * 72];
    const int tid = threadIdx.x;
    const int m0 = blockIdx.x * 128;
    const int y = blockIdx.y;
    const int n0 = y * 256;
    const int lane = tid & 63, wid = tid >> 6;
    const int wm = wid >> 2, wn = wid & 3;
    const int cl = lane & 15, r4 = (lane >> 4) * 4;

    f32x4 acc[4][4] = {};

    for (int kc = 0; kc < 4; ++kc) {
        __syncthreads();
        // stage A tile 128x64 (coalesced 16B, zero-pad OOB rows)
        {
            int r = tid >> 3, c8 = (tid & 7) * 8;
            #pragma unroll
            for (int h = 0; h < 2; ++h, r += 64) {
                uint4 v = make_uint4(0u, 0u, 0u, 0u);
                if (m0 + r < M)
                    v = *reinterpret_cast<const uint4*>(A + (size_t)(m0 + r) * 256 + kc * 64 + c8);
                *reinterpret_cast<uint4*>(a_s + r * 72 + c8) = v;
            }
        }
        // stage W tile 256x64 (rows n0..n0+255 of Wt, guard n<640)
        {
            int n = tid >> 3, c8 = (tid & 7) * 8;
            #pragma unroll
            for (int q = 0; q < 4; ++q, n += 64) {
                uint4 v = make_uint4(0u, 0u, 0u, 0u);
                if (n0 + n < 640)
                    v = *reinterpret_cast<const uint4*>(Wt + (size_t)(n0 + n) * 256 + kc * 64 + c8);
                *reinterpret_cast<uint4*>(w_s + n * 72 + c8) = v;
            }
        }
        __syncthreads();
        bf16x8 af[4][2], bfr[4][2];
        #pragma unroll
        for (int i = 0; i < 4; ++i)
            #pragma unroll
            for (int kk = 0; kk < 2; ++kk) {
                int m = wm * 64 + i * 16 + cl;
                int k = kk * 32 + (lane >> 4) * 8;
                af[i][kk] = *reinterpret_cast<const bf16x8*>(a_s + m * 72 + k);
            }
        #pragma unroll
        for (int j = 0; j < 4; ++j)
            #pragma unroll
            for (int kk = 0; kk < 2; ++kk) {
                int n = wn * 64 + j * 16 + cl;
                int k = kk * 32 + (lane >> 4) * 8;
                bfr[j][kk] = *reinterpret_cast<const bf16x8*>(w_s + n * 72 + k);
            }
        #pragma unroll
        for (int kk = 0; kk < 2; ++kk)
            #pragma unroll
            for (int i = 0; i < 4; ++i)
                #pragma unroll
                for (int j = 0; j < 4; ++j)
                    acc[i][j] = __builtin_amdgcn_mfma_f32_16x16x32_bf16(
                        af[i][kk], bfr[j][kk], acc[i][j], 0, 0, 0);
    }

    if (y < 2) {
        unsigned short* dst = (y == 0) ? value : offr;
        const float* bias = (y == 0) ? b_val : b_off;
        #pragma unroll
        for (int j = 0; j < 4; ++j) {
            int col = wn * 64 + j * 16 + cl;
            float bv = bias[col];
            #pragma unroll
            for (int i = 0; i < 4; ++i) {
                int mb = wm * 64 + i * 16 + r4;
                #pragma unroll
                for (int r = 0; r < 4; ++r) {
                    int row = m0 + mb + r;
                    if (row < M)
                        dst[(size_t)row * 256 + col] = f2bf(acc[i][j][r] + bv);
                }
            }
        }
    } else if (wn < 2) {
        #pragma unroll
        for (int j = 0; j < 4; ++j) {
            int a = wn * 64 + j * 16 + cl;   // att col 0..127; one head per 16 lanes
            float bv = b_att[a];
            #pragma unroll
            for (int i = 0; i < 4; ++i) {
                #pragma unroll
                for (int r = 0; r < 4; ++r) {
                    float v = acc[i][j][r] + bv;
                    float mx = v;
                    mx = fmaxf(mx, __shfl_xor(mx, 1));
                    mx = fmaxf(mx, __shfl_xor(mx, 2));
                    mx = fmaxf(mx, __shfl_xor(mx, 4));
                    mx = fmaxf(mx, __shfl_xor(mx, 8));
                    float e = __expf(v - mx);
                    float s = e;
                    s += __shfl_xor(s, 1);
                    s += __shfl_xor(s, 2);
                    s += __shfl_xor(s, 4);
                    s += __shfl_xor(s, 8);
                    int row = m0 + wm * 64 + i * 16 + r4 + r;
                    if (row < M)
                        attw[(size_t)row * 128 + a] = f2bf(e / s);
                }
            }
        }
    }
}

// ---------------------------------------------------------------------------
// Deformable sampling core (bf16 gathers). 32 lanes per (token, head).
// ---------------------------------------------------------------------------
__global__ __launch_bounds__(256)
void k_sample(const unsigned short* __restrict__ value,
              const unsigned short* __restrict__ offr,
              const unsigned short* __restrict__ attw,
              const float* __restrict__ ref,
              const int* __restrict__ shapes, const int* __restrict__ lsi,
              unsigned short* __restrict__ core, int M)
{
    const int tid = threadIdx.x;
    const int pair = blockIdx.x * 8 + (tid >> 5);
    const int d = tid & 31;
    const int tok = pair >> 3, h = pair & 7;
    if (tok >= M) return;

    const int nk = lsi[3] + shapes[6] * shapes[7];
    const int b = tok / nk;
    const unsigned short* vb = value + (size_t)b * nk * 256;

    float acc = 0.f;
    #pragma unroll
    for (int l = 0; l < LEVELS; ++l) {
        const int Hl = shapes[l * 2], Wl = shapes[l * 2 + 1];
        const float rx = ref[(size_t)tok * 8 + l * 2 + 0];
        const float ry = ref[(size_t)tok * 8 + l * 2 + 1];
        const unsigned short* vl = vb + (size_t)lsi[l] * 256 + h * 32 + d;
        #pragma unroll
        for (int p = 0; p < POINTS; ++p) {
            const int oi = tok * 256 + h * 32 + l * 8 + p * 2;
            unsigned int oxy = *reinterpret_cast<const unsigned int*>(offr + oi);
            const float ox = bf2f((unsigned short)(oxy & 0xffffu));
            const float oy = bf2f((unsigned short)(oxy >> 16));
            const float aw = bf2f(attw[tok * 128 + h * 16 + l * 4 + p]);
            const float x = (rx + ox / (float)Wl) * (float)Wl - 0.5f;
            const float y = (ry + oy / (float)Hl) * (float)Hl - 0.5f;
            const float x0f = floorf(x), y0f = floorf(y);
            const float fx = x - x0f, fy = y - y0f;
            const int x0 = (int)x0f, y0 = (int)y0f;
            #pragma unroll
            for (int t = 0; t < 4; ++t) {
                const int dx = t & 1, dy = t >> 1;
                const int xi = x0 + dx, yi = y0 + dy;
                const bool valid = (xi >= 0) & (xi < Wl) & (yi >= 0) & (yi < Hl);
                const float w = (dx ? fx : 1.f - fx) * (dy ? fy : 1.f - fy);
                const int xc = min(max(xi, 0), Wl - 1);
                const int yc = min(max(yi, 0), Hl - 1);
                const float v = bf2f(vl[(size_t)(yc * Wl + xc) * 256]);
                acc += valid ? (w * aw) * v : 0.f;
            }
        }
    }
    core[(size_t)tok * 256 + h * 32 + d] = f2bf(acc);
}

// ---------------------------------------------------------------------------
// Out-projection + residual + LN1: x_bf = LN(src + core_bf @ wout + b_out)
// Same MFMA core as k_proj; BN=256 = full row so LN reduces in-block.
// ---------------------------------------------------------------------------
__global__ __launch_bounds__(512)
void k_oproj(const unsigned short* __restrict__ A, const unsigned short* __restrict__ Wt,
             const float* __restrict__ b_out, const float* __restrict__ src,
             const float* __restrict__ g1, const float* __restrict__ bt1,
             unsigned short* __restrict__ X, int M)
{
    __shared__ unsigned short a_s[128 * 72];
    __shared__ unsigned short w_s[256 * 72];
    __shared__ float red[128 * 8];
    __shared__ float mr[128 * 2];
    const int tid = threadIdx.x;
    const int m0 = blockIdx.x * 128;
    const int lane = tid & 63, wid = tid >> 6;
    const int wm = wid >> 2, wn = wid & 3;
    const int cl = lane & 15, r4 = (lane >> 4) * 4;

    f32x4 acc[4][4] = {};

    for (int kc = 0; kc < 4; ++kc) {
        __syncthreads();
        {
            int r = tid >> 3, c8 = (tid & 7) * 8;
            #pragma unroll
            for (int h = 0; h < 2; ++h, r += 64) {
                uint4 v = make_uint4(0u, 0u, 0u, 0u);
                if (m0 + r < M)
                    v = *reinterpret_cast<const uint4*>(A + (size_t)(m0 + r) * 256 + kc * 64 + c8);
                *reinterpret_cast<uint4*>(a_s + r * 72 + c8) = v;
            }
        }
        {
            int n = tid >> 3, c8 = (tid & 7) * 8;
            #pragma unroll
            for (int q = 0; q < 4; ++q, n += 64) {
                uint4 v = *reinterpret_cast<const uint4*>(Wt + (size_t)n * 256 + kc * 64 + c8);
                *reinterpret_cast<uint4*>(w_s + n * 72 + c8) = v;
            }
        }
        __syncthreads();
        bf16x8 af[4][2], bfr[4][2];
        #pragma unroll
        for (int i = 0; i < 4; ++i)
            #pragma unroll
            for (int kk = 0; kk < 2; ++kk) {
                int m = wm * 64 + i * 16 + cl;
                int k = kk * 32 + (lane >> 4) * 8;
                af[i][kk] = *reinterpret_cast<const bf16x8*>(a_s + m * 72 + k);
            }
        #pragma unroll
        for (int j = 0; j < 4; ++j)
            #pragma unroll
            for (int kk = 0; kk < 2; ++kk) {
                int n = wn * 64 + j * 16 + cl;
                int k = kk * 32 + (lane >> 4) * 8;
                bfr[j][kk] = *reinterpret_cast<const bf16x8*>(w_s + n * 72 + k);
            }
        #pragma unroll
        for (int kk = 0; kk < 2; ++kk)
            #pragma unroll
            for (int i = 0; i < 4; ++i)
                #pragma unroll
                for (int j = 0; j < 4; ++j)
                    acc[i][j] = __builtin_amdgcn_mfma_f32_16x16x32_bf16(
                        af[i][kk], bfr[j][kk], acc[i][j], 0, 0, 0);
    }

    // v = acc + bias + src (residual)
    #pragma unroll
    for (int j = 0; j < 4; ++j) {
        int col = wn * 64 + j * 16 + cl;
        float bv = b_out[col];
        #pragma unroll
        for (int i = 0; i < 4; ++i) {
            int mb = wm * 64 + i * 16 + r4;
            #pragma unroll
            for (int r = 0; r < 4; ++r) {
                int row = m0 + mb + r;
                float sv = (row < M) ? src[(size_t)row * 256 + col] : 0.f;
                acc[i][j][r] += bv + sv;
            }
        }
    }
    // per-row mean/var: in-lane over j, shfl over 16-lane col group, LDS over wn
    #pragma unroll
    for (int i = 0; i < 4; ++i)
        #pragma unroll
        for (int r = 0; r < 4; ++r) {
            float s1 = 0.f, s2 = 0.f;
            #pragma unroll
            for (int j = 0; j < 4; ++j) { float t = acc[i][j][r]; s1 += t; s2 += t * t; }
            s1 += __shfl_xor(s1, 1); s2 += __shfl_xor(s2, 1);
            s1 += __shfl_xor(s1, 2); s2 += __shfl_xor(s2, 2);
            s1 += __shfl_xor(s1, 4); s2 += __shfl_xor(s2, 4);
            s1 += __shfl_xor(s1, 8); s2 += __shfl_xor(s2, 8);
            if (cl == 0) {
                int rr = wm * 64 + i * 16 + r4 + r;
                red[(rr * 4 + wn) * 2 + 0] = s1;
                red[(rr * 4 + wn) * 2 + 1] = s2;
            }
        }
    __syncthreads();
    if (tid < 128) {
        float s1 = red[tid * 8] + red[tid * 8 + 2] + red[tid * 8 + 4] + red[tid * 8 + 6];
        float s2 = red[tid * 8 + 1] + red[tid * 8 + 3] + red[tid * 8 + 5] + red[tid * 8 + 7];
        float mu = s1 * (1.f / 256.f);
        mr[tid * 2] = mu;
        mr[tid * 2 + 1] = rsqrtf(fmaxf(s2 * (1.f / 256.f) - mu * mu, 0.f) + 1e-5f);
    }
    __syncthreads();
    #pragma unroll
    for (int j = 0; j < 4; ++j) {
        int col = wn * 64 + j * 16 + cl;
        float gv = g1[col], bt = bt1[col];
        #pragma unroll
        for (int i = 0; i < 4; ++i) {
            int mb = wm * 64 + i * 16 + r4;
            #pragma unroll
            for (int r = 0; r < 4; ++r) {
                int rr = mb + r, row = m0 + rr;
                if (row < M)
                    X[(size_t)row * 256 + col] =
                        f2bf((acc[i][j][r] - mr[rr * 2]) * mr[rr * 2 + 1] * gv + bt);
            }
        }
    }
}

// ---------------------------------------------------------------------------
// Fused FFN + residual + LN2: out = LN(x + relu(x@W1+b1)@W2 + b2)
// Per 256-col chunk: GEMM1 (MFMA) -> relu -> h in LDS (bf16) -> GEMM2 accum.
// LDS: x 66K + h 66K + w 20K + red 5K = 157 KB (1 block/CU, 8 waves).
// ---------------------------------------------------------------------------
__global__ __launch_bounds__(512)
void k_ffn(const unsigned short* __restrict__ Xbf, const unsigned short* __restrict__ W1t,
           const float* __restrict__ B1, const unsigned short* __restrict__ W2t,
           const float* __restrict__ B2, const float* __restrict__ G2,
           const float* __restrict__ BT2, float* __restrict__ OUT, int M)
{
    __shared__ unsigned short x_s[128 * 264];
    __shared__ unsigned short h_s[128 * 264];
    __shared__ unsigned short w_s[256 * 40];
    __shared__ float red[128 * 8];
    __shared__ float mr[128 * 2];
    const int tid = threadIdx.x;
    const int m0 = blockIdx.x * 128;
    const int lane = tid & 63, wid = tid >> 6;
    const int wm = wid >> 2, wn = wid & 3;
    const int cl = lane & 15, r4 = (lane >> 4) * 4;

    // stage x tile (128x256 bf16), resident for both GEMMs + residual
    #pragma unroll
    for (int it = 0; it < 8; ++it) {
        int id = tid + it * 512;
        int r = id >> 5, c8 = id & 31;
        uint4 v = make_uint4(0u, 0u, 0u, 0u);
        if (m0 + r < M)
            v = *reinterpret_cast<const uint4*>(Xbf + (size_t)(m0 + r) * 256 + c8 * 8);
        *reinterpret_cast<uint4*>(x_s + r * 264 + c8 * 8) = v;
    }

    f32x4 acc2[4][4] = {};

    for (int cc = 0; cc < 4; ++cc) {
        // ---- GEMM1: h_chunk = relu(x @ W1[:, cc*256 : cc*256+256] + b1) ----
        f32x4 acc1[4][4] = {};
        for (int ks = 0; ks < 8; ++ks) {
            __syncthreads();
            {   // stage W1t slice [256 n][32 k]
                int n = tid >> 1, cb = (tid & 1) * 2;
                #pragma unroll
                for (int e = 0; e < 2; ++e) {
                    uint4 v = *reinterpret_cast<const uint4*>(
                        W1t + (size_t)(cc * 256 + n) * 256 + ks * 32 + (cb + e) * 8);
                    *reinterpret_cast<uint4*>(w_s + n * 40 + (cb + e) * 8) = v;
                }
            }
            __syncthreads();
            bf16x8 bfr[4];
            #pragma unroll
            for (int j = 0; j < 4; ++j) {
                int n = wn * 64 + j * 16 + cl;
                bfr[j] = *reinterpret_cast<const bf16x8*>(w_s + n * 40 + (lane >> 4) * 8);
            }
            #pragma unroll
            for (int i = 0; i < 4; ++i) {
                int m = wm * 64 + i * 16 + cl;
                int k = ks * 32 + (lane >> 4) * 8;
                bf16x8 a = *reinterpret_cast<const bf16x8*>(x_s + m * 264 + k);
                #pragma unroll
                for (int j = 0; j < 4; ++j)
                    acc1[i][j] = __builtin_amdgcn_mfma_f32_16x16x32_bf16(
                        a, bfr[j], acc1[i][j], 0, 0, 0);
            }
        }
        // write h chunk to LDS as bf16 (barrier below in GEMM2 loop covers vis)
        #pragma unroll
        for (int j = 0; j < 4; ++j) {
            int kl = wn * 64 + j * 16 + cl;
            float bv = B1[cc * 256 + kl];
            #pragma unroll
            for (int i = 0; i < 4; ++i) {
                int m = wm * 64 + i * 16 + r4;
                #pragma unroll
                for (int r = 0; r < 4; ++r)
                    h_s[(m + r) * 264 + kl] = f2bf(fmaxf(acc1[i][j][r] + bv, 0.f));
            }
        }
        // ---- GEMM2: acc2 += h_chunk @ W2[cc*256 : cc*256+256, :] ----
        for (int ks = 0; ks < 8; ++ks) {
            __syncthreads();
            {   // stage W2t slice [256 n][32 k], k0 = cc*256 + ks*32
                int n = tid >> 1, cb = (tid & 1) * 2;
                #pragma unroll
                for (int e = 0; e < 2; ++e) {
                    uint4 v = *reinterpret_cast<const uint4*>(
                        W2t + (size_t)n * 1024 + cc * 256 + ks * 32 + (cb + e) * 8);
                    *reinterpret_cast<uint4*>(w_s + n * 40 + (cb + e) * 8) = v;
                }
            }
            __syncthreads();
            bf16x8 bfr[4];
            #pragma unroll
            for (int j = 0; j < 4; ++j) {
                int n = wn * 64 + j * 16 + cl;
                bfr[j] = *reinterpret_cast<const bf16x8*>(w_s + n * 40 + (lane >> 4) * 8);
            }
            #pragma unroll
            for (int i = 0; i < 4; ++i) {
                int m = wm * 64 + i * 16 + cl;
                int k = ks * 32 + (lane >> 4) * 8;
                bf16x8 a = *reinterpret_cast<const bf16x8*>(h_s + m * 264 + k);
                #pragma unroll
                for (int j = 0; j < 4; ++j)
                    acc2[i][j] = __builtin_amdgcn_mfma_f32_16x16x32_bf16(
                        a, bfr[j], acc2[i][j], 0, 0, 0);
            }
        }
    }

    // epilogue: v = acc2 + b2 + x; LN; store fp32
    #pragma unroll
    for (int j = 0; j < 4; ++j) {
        int col = wn * 64 + j * 16 + cl;
        float bv = B2[col];
        #pragma unroll
        for (int i = 0; i < 4; ++i) {
            int mb = wm * 64 + i * 16 + r4;
            #pragma unroll
            for (int r = 0; r < 4; ++r) {
                float xv = bf2f(x_s[(mb + r) * 264 + col]);
                acc2[i][j][r] += bv + xv;
            }
        }
    }
    #pragma unroll
    for (int i = 0; i < 4; ++i)
        #pragma unroll
        for (int r = 0; r < 4; ++r) {
            float s1 = 0.f, s2 = 0.f;
            #pragma unroll
            for (int j = 0; j < 4; ++j) { float t = acc2[i][j][r]; s1 += t; s2 += t * t; }
            s1 += __shfl_xor(s1, 1); s2 += __shfl_xor(s2, 1);
            s1 += __shfl_xor(s1, 2); s2 += __shfl_xor(s2, 2);
            s1 += __shfl_xor(s1, 4); s2 += __shfl_xor(s2, 4);
            s1 += __shfl_xor(s1, 8); s2 += __shfl_xor(s2, 8);
            if (cl == 0) {
                int rr = wm * 64 + i * 16 + r4 + r;
                red[(rr * 4 + wn) * 2 + 0] = s1;
                red[(rr * 4 + wn) * 2 + 1] = s2;
            }
        }
    __syncthreads();
    if (tid < 128) {
        float s1 = red[tid * 8] + red[tid * 8 + 2] + red[tid * 8 + 4] + red[tid * 8 + 6];
        float s2 = red[tid * 8 + 1] + red[tid * 8 + 3] + red[tid * 8 + 5] + red[tid * 8 + 7];
        float mu = s1 * (1.f / 256.f);
        mr[tid * 2] = mu;
        mr[tid * 2 + 1] = rsqrtf(fmaxf(s2 * (1.f / 256.f) - mu * mu, 0.f) + 1e-5f);
    }
    __syncthreads();
    #pragma unroll
    for (int j = 0; j < 4; ++j) {
        int col = wn * 64 + j * 16 + cl;
        float gv = G2[col], bt = BT2[col];
        #pragma unroll
        for (int i = 0; i < 4; ++i) {
            int mb = wm * 64 + i * 16 + r4;
            #pragma unroll
            for (int r = 0; r < 4; ++r) {
                int rr = mb + r, row = m0 + rr;
                if (row < M)
                    OUT[(size_t)row * 256 + col] =
                        (acc2[i][j][r] - mr[rr * 2]) * mr[rr * 2 + 1] * gv + bt;
            }
        }
    }
}

// ---------------------------------------------------------------------------
extern "C" void kernel_launch(void* const* d_in, const int* in_sizes, int n_in,
                              void* d_out, int out_size, void* d_ws, size_t ws_size,
                              hipStream_t stream) {
    const float* src    = (const float*)d_in[0];
    const float* ref    = (const float*)d_in[1];
    const int*   shapes = (const int*)d_in[2];
    const int*   lsi    = (const int*)d_in[3];
    const float* b_off  = (const float*)d_in[5];
    const float* b_att  = (const float*)d_in[7];
    const float* b_val  = (const float*)d_in[9];
    const float* b_out  = (const float*)d_in[11];
    const float* g1     = (const float*)d_in[12];
    const float* bt1    = (const float*)d_in[13];
    const float* b1     = (const float*)d_in[15];
    const float* b2     = (const float*)d_in[17];
    const float* g2     = (const float*)d_in[18];
    const float* bt2    = (const float*)d_in[19];
    const float* w_off  = (const float*)d_in[4];
    const float* w_att  = (const float*)d_in[6];
    const float* w_val  = (const float*)d_in[8];
    const float* w_out  = (const float*)d_in[10];
    const float* w1     = (const float*)d_in[14];
    const float* w2     = (const float*)d_in[16];

    const int M = in_sizes[0] / EMBED;  // B*nq = 49130
    const size_t M256 = (size_t)M * 256;

    unsigned short* w16     = (unsigned short*)d_ws;
    unsigned short* src_bf  = w16;
    unsigned short* value_bf = src_bf + M256;
    unsigned short* offr_bf = value_bf + M256;
    unsigned short* core_bf = offr_bf + M256;
    unsigned short* x_bf    = core_bf + M256;
    unsigned short* attw_bf = x_bf + M256;               // M*128
    unsigned short* wcat    = attw_bf + (size_t)M * 128; // 640*256
    unsigned short* woutt   = wcat + 163840;             // 256*256
    unsigned short* w1t     = woutt + 65536;             // 1024*256
    unsigned short* w2t     = w1t + 262144;              // 256*1024

    const int gb128 = (M + 127) / 128;

    k_cvt_src<<<4096, 256, 0, stream>>>(src, src_bf, M * 256);
    k_cvt_w<<<2944, 256, 0, stream>>>(w_val, w_off, w_att, w_out, w1, w2,
                                      wcat, woutt, w1t, w2t);
    k_proj<<<dim3(gb128, 3), 512, 0, stream>>>(src_bf, wcat, b_val, b_off, b_att,
                                               value_bf, offr_bf, attw_bf, M);
    k_sample<<<M, 256, 0, stream>>>(value_bf, offr_bf, attw_bf, ref, shapes, lsi,
                                    core_bf, M);
    k_oproj<<<gb128, 512, 0, stream>>>(core_bf, woutt, b_out, src, g1, bt1, x_bf, M);
    k_ffn<<<gb128, 512, 0, stream>>>(x_bf, w1t, b1, w2t, b2, g2, bt2,
                                     (float*)d_out, M);
}

// Round 3
// 424.381 us; speedup vs baseline: 6.8897x; 2.6799x over previous
//
#include <hip/hip_runtime.h>
#include <math.h>

#define EMBED 256
#define HEADS 8
#define LEVELS 4
#define POINTS 4
#define FFNDIM 1024

typedef float f32x4 __attribute__((ext_vector_type(4)));
typedef __bf16 bf16x8 __attribute__((ext_vector_type(8)));

static __device__ __forceinline__ float4 ld4f(const float* p) {
    return *reinterpret_cast<const float4*>(p);
}
static __device__ __forceinline__ unsigned short f2bf(float f) {
    unsigned int u = __float_as_uint(f);
    unsigned int r = (u + 0x7fffu + ((u >> 16) & 1u)) >> 16;
    return (unsigned short)r;
}
static __device__ __forceinline__ float bf2f(unsigned short u) {
    return __uint_as_float((unsigned int)u << 16);
}

// ---------------------------------------------------------------------------
// fp32 -> bf16 (RNE) elementwise, vectorized
// ---------------------------------------------------------------------------
__global__ __launch_bounds__(256)
void k_cvt_src(const float* __restrict__ src, unsigned short* __restrict__ dst, int n)
{
    int i = (blockIdx.x * 256 + threadIdx.x) * 4;
    const int stride = gridDim.x * 1024;
    for (; i < n; i += stride) {
        float4 v = ld4f(src + i);
        ushort4 o;
        o.x = f2bf(v.x); o.y = f2bf(v.y); o.z = f2bf(v.z); o.w = f2bf(v.w);
        *reinterpret_cast<ushort4*>(dst + i) = o;
    }
}

// ---------------------------------------------------------------------------
// Weight transpose + convert: Wt[n][k] = bf16(W[k][n]) for all weights.
// ---------------------------------------------------------------------------
__global__ __launch_bounds__(256)
void k_cvt_w(const float* __restrict__ wv, const float* __restrict__ wo,
             const float* __restrict__ wa, const float* __restrict__ wout,
             const float* __restrict__ w1, const float* __restrict__ w2,
             unsigned short* __restrict__ wcat, unsigned short* __restrict__ woutt,
             unsigned short* __restrict__ w1t, unsigned short* __restrict__ w2t)
{
    const int total = 163840 + 65536 + 262144 + 262144;
    for (int gid = blockIdx.x * 256 + threadIdx.x; gid < total; gid += gridDim.x * 256) {
        int local = gid;
        float f; unsigned short* dst;
        if (local < 163840) {                       // wcat_t [640][256]
            int n = local >> 8, k = local & 255;
            if (n < 256)      f = wv[k * 256 + n];
            else if (n < 512) f = wo[k * 256 + (n - 256)];
            else              f = wa[k * 128 + (n - 512)];
            dst = wcat + local;
        } else if ((local -= 163840) < 65536) {     // wout_t [256][256]
            int n = local >> 8, k = local & 255;
            f = wout[k * 256 + n];
            dst = woutt + local;
        } else if ((local -= 65536) < 262144) {     // w1_t [1024][256]
            int n = local >> 8, k = local & 255;
            f = w1[k * 1024 + n];
            dst = w1t + local;
        } else {                                    // w2_t [256][1024]
            local -= 262144;
            int n = local >> 10, k = local & 1023;
            f = w2[k * 256 + n];
            dst = w2t + local;
        }
        *dst = f2bf(f);
    }
}

// ---------------------------------------------------------------------------
// Projection GEMM: [value|off|att](M,640) = src_bf(M,256) @ wcat_t^T + bias
// grid.y: 0=value, 1=off, 2=att(fused softmax16).
// ---------------------------------------------------------------------------
__global__ __launch_bounds__(512)
void k_proj(const unsigned short* __restrict__ A, const unsigned short* __restrict__ Wt,
            const float* __restrict__ b_val, const float* __restrict__ b_off,
            const float* __restrict__ b_att,
            unsigned short* __restrict__ value, unsigned short* __restrict__ offr,
            unsigned short* __restrict__ attw, int M)
{
    __shared__ unsigned short a_s[128 * 72];
    __shared__ unsigned short w_s[256 * 72];
    const int tid = threadIdx.x;
    const int m0 = blockIdx.x * 128;
    const int y = blockIdx.y;
    const int n0 = y * 256;
    const int lane = tid & 63, wid = tid >> 6;
    const int wm = wid >> 2, wn = wid & 3;
    const int cl = lane & 15, r4 = (lane >> 4) * 4;

    f32x4 acc[4][4] = {};

    for (int kc = 0; kc < 4; ++kc) {
        __syncthreads();
        {
            int r = tid >> 3, c8 = (tid & 7) * 8;
            #pragma unroll
            for (int h = 0; h < 2; ++h, r += 64) {
                uint4 v = make_uint4(0u, 0u, 0u, 0u);
                if (m0 + r < M)
                    v = *reinterpret_cast<const uint4*>(A + (size_t)(m0 + r) * 256 + kc * 64 + c8);
                *reinterpret_cast<uint4*>(a_s + r * 72 + c8) = v;
            }
        }
        {
            int n = tid >> 3, c8 = (tid & 7) * 8;
            #pragma unroll
            for (int q = 0; q < 4; ++q, n += 64) {
                uint4 v = make_uint4(0u, 0u, 0u, 0u);
                if (n0 + n < 640)
                    v = *reinterpret_cast<const uint4*>(Wt + (size_t)(n0 + n) * 256 + kc * 64 + c8);
                *reinterpret_cast<uint4*>(w_s + n * 72 + c8) = v;
            }
        }
        __syncthreads();
        bf16x8 af[4][2], bfr[4][2];
        #pragma unroll
        for (int i = 0; i < 4; ++i)
            #pragma unroll
            for (int kk = 0; kk < 2; ++kk) {
                int m = wm * 64 + i * 16 + cl;
                int k = kk * 32 + (lane >> 4) * 8;
                af[i][kk] = *reinterpret_cast<const bf16x8*>(a_s + m * 72 + k);
            }
        #pragma unroll
        for (int j = 0; j < 4; ++j)
            #pragma unroll
            for (int kk = 0; kk < 2; ++kk) {
                int n = wn * 64 + j * 16 + cl;
                int k = kk * 32 + (lane >> 4) * 8;
                bfr[j][kk] = *reinterpret_cast<const bf16x8*>(w_s + n * 72 + k);
            }
        #pragma unroll
        for (int kk = 0; kk < 2; ++kk)
            #pragma unroll
            for (int i = 0; i < 4; ++i)
                #pragma unroll
                for (int j = 0; j < 4; ++j)
                    acc[i][j] = __builtin_amdgcn_mfma_f32_16x16x32_bf16(
                        af[i][kk], bfr[j][kk], acc[i][j], 0, 0, 0);
    }

    if (y < 2) {
        unsigned short* dst = (y == 0) ? value : offr;
        const float* bias = (y == 0) ? b_val : b_off;
        #pragma unroll
        for (int j = 0; j < 4; ++j) {
            int col = wn * 64 + j * 16 + cl;
            float bv = bias[col];
            #pragma unroll
            for (int i = 0; i < 4; ++i) {
                int mb = wm * 64 + i * 16 + r4;
                #pragma unroll
                for (int r = 0; r < 4; ++r) {
                    int row = m0 + mb + r;
                    if (row < M)
                        dst[(size_t)row * 256 + col] = f2bf(acc[i][j][r] + bv);
                }
            }
        }
    } else if (wn < 2) {
        #pragma unroll
        for (int j = 0; j < 4; ++j) {
            int a = wn * 64 + j * 16 + cl;   // att col; one head per 16 lanes
            float bv = b_att[a];
            #pragma unroll
            for (int i = 0; i < 4; ++i) {
                #pragma unroll
                for (int r = 0; r < 4; ++r) {
                    float v = acc[i][j][r] + bv;
                    float mx = v;
                    mx = fmaxf(mx, __shfl_xor(mx, 1));
                    mx = fmaxf(mx, __shfl_xor(mx, 2));
                    mx = fmaxf(mx, __shfl_xor(mx, 4));
                    mx = fmaxf(mx, __shfl_xor(mx, 8));
                    float e = __expf(v - mx);
                    float s = e;
                    s += __shfl_xor(s, 1);
                    s += __shfl_xor(s, 2);
                    s += __shfl_xor(s, 4);
                    s += __shfl_xor(s, 8);
                    int row = m0 + wm * 64 + i * 16 + r4 + r;
                    if (row < M)
                        attw[(size_t)row * 128 + a] = f2bf(e / s);
                }
            }
        }
    }
}

// ---------------------------------------------------------------------------
// Deformable sampling, two-phase.
// Block = 4 tokens, 256 threads.
// Phase 1: 512 point-tasks (tok,h,l,p) -> 4 corner {idx,w} pairs into LDS.
//   idx pre-multiplied to u32-element pixel offset; w = bilinear*attn (0 if
//   invalid). LDS [4][8][65] int2: per-head stride 520B -> broadcast reads
//   from 8 heads land on distinct bank pairs (conflict-free).
// Phase 2: thread = (tok, h, channel-quad). 64 x { ds_read_b64 broadcast,
//   uint2 gather (4 bf16 ch), 4 unpack, 4 FMA }.
// ---------------------------------------------------------------------------
__global__ __launch_bounds__(256)
void k_sample(const unsigned short* __restrict__ value,
              const unsigned short* __restrict__ offr,
              const unsigned short* __restrict__ attw,
              const float* __restrict__ ref,
              const int* __restrict__ shapes, const int* __restrict__ lsi,
              unsigned short* __restrict__ core, int M)
{
    __shared__ int2 iw_s[4][8][65];
    const int tid = threadIdx.x;
    const int tok0 = blockIdx.x * 4;
    const int nk = lsi[3] + shapes[6] * shapes[7];

    // ---- phase 1: per-point index/weight computation ----
    #pragma unroll
    for (int q = 0; q < 2; ++q) {
        const int task = tid + q * 256;
        const int tl = task >> 7;
        const int rest = task & 127;          // h*16 + l*4 + p
        const int l = (rest >> 2) & 3;
        const int lp = rest & 15;
        const int hh = rest >> 4;
        const int tok = tok0 + tl;
        int2 out[4];
        if (tok < M) {
            const int Hl = shapes[l * 2], Wl = shapes[l * 2 + 1];
            const int base = (tok / nk) * nk + lsi[l];
            const float rx = ref[(size_t)tok * 8 + l * 2];
            const float ry = ref[(size_t)tok * 8 + l * 2 + 1];
            const unsigned int oxy =
                *reinterpret_cast<const unsigned int*>(offr + (size_t)tok * 256 + rest * 2);
            const float ox = bf2f((unsigned short)(oxy & 0xffffu));
            const float oy = bf2f((unsigned short)(oxy >> 16));
            const float aw = bf2f(attw[(size_t)tok * 128 + rest]);
            const float x = (rx + ox / (float)Wl) * (float)Wl - 0.5f;
            const float y = (ry + oy / (float)Hl) * (float)Hl - 0.5f;
            const float x0f = floorf(x), y0f = floorf(y);
            const float fx = x - x0f, fy = y - y0f;
            const int x0 = (int)x0f, y0 = (int)y0f;
            #pragma unroll
            for (int t = 0; t < 4; ++t) {
                const int dx = t & 1, dy = t >> 1;
                const int xi = x0 + dx, yi = y0 + dy;
                const bool valid = (xi >= 0) & (xi < Wl) & (yi >= 0) & (yi < Hl);
                const float w = (dx ? fx : 1.f - fx) * (dy ? fy : 1.f - fy) * aw;
                const int xc = min(max(xi, 0), Wl - 1);
                const int yc = min(max(yi, 0), Hl - 1);
                out[t].x = (base + yc * Wl + xc) * 128;   // u32-element pixel offset
                out[t].y = __float_as_int(valid ? w : 0.f);
            }
        } else {
            #pragma unroll
            for (int t = 0; t < 4; ++t) out[t] = make_int2(0, 0);
        }
        #pragma unroll
        for (int t = 0; t < 4; ++t)
            iw_s[tl][hh][lp * 4 + t] = out[t];
    }
    __syncthreads();

    // ---- phase 2: gather + accumulate ----
    const int tl = tid >> 6;
    const int h = (tid >> 3) & 7;
    const int dp = tid & 7;                  // channel quad: ch 4dp..4dp+3
    const int tok = tok0 + tl;
    const unsigned int* vu = reinterpret_cast<const unsigned int*>(value);
    const int choff = h * 16 + dp * 2;       // u32 offset within pixel
    const int2* pt = &iw_s[tl][h][0];
    float a0 = 0.f, a1 = 0.f, a2 = 0.f, a3 = 0.f;
    #pragma unroll 16
    for (int q = 0; q < 64; ++q) {
        const int2 iw = pt[q];
        const float w = __int_as_float(iw.y);
        const uint2 v = *reinterpret_cast<const uint2*>(vu + (size_t)(unsigned)iw.x + choff);
        a0 += w * __uint_as_float(v.x << 16);
        a1 += w * __uint_as_float(v.x & 0xffff0000u);
        a2 += w * __uint_as_float(v.y << 16);
        a3 += w * __uint_as_float(v.y & 0xffff0000u);
    }
    if (tok < M) {
        unsigned int o0 = (unsigned int)f2bf(a0) | ((unsigned int)f2bf(a1) << 16);
        unsigned int o1 = (unsigned int)f2bf(a2) | ((unsigned int)f2bf(a3) << 16);
        *reinterpret_cast<uint2*>(core + (size_t)tok * 256 + choff * 2) = make_uint2(o0, o1);
    }
}

// ---------------------------------------------------------------------------
// Out-projection + residual + LN1: x_bf = LN(src + core_bf @ wout + b_out)
// ---------------------------------------------------------------------------
__global__ __launch_bounds__(512)
void k_oproj(const unsigned short* __restrict__ A, const unsigned short* __restrict__ Wt,
             const float* __restrict__ b_out, const float* __restrict__ src,
             const float* __restrict__ g1, const float* __restrict__ bt1,
             unsigned short* __restrict__ X, int M)
{
    __shared__ unsigned short a_s[128 * 72];
    __shared__ unsigned short w_s[256 * 72];
    __shared__ float red[128 * 8];
    __shared__ float mr[128 * 2];
    const int tid = threadIdx.x;
    const int m0 = blockIdx.x * 128;
    const int lane = tid & 63, wid = tid >> 6;
    const int wm = wid >> 2, wn = wid & 3;
    const int cl = lane & 15, r4 = (lane >> 4) * 4;

    f32x4 acc[4][4] = {};

    for (int kc = 0; kc < 4; ++kc) {
        __syncthreads();
        {
            int r = tid >> 3, c8 = (tid & 7) * 8;
            #pragma unroll
            for (int h = 0; h < 2; ++h, r += 64) {
                uint4 v = make_uint4(0u, 0u, 0u, 0u);
                if (m0 + r < M)
                    v = *reinterpret_cast<const uint4*>(A + (size_t)(m0 + r) * 256 + kc * 64 + c8);
                *reinterpret_cast<uint4*>(a_s + r * 72 + c8) = v;
            }
        }
        {
            int n = tid >> 3, c8 = (tid & 7) * 8;
            #pragma unroll
            for (int q = 0; q < 4; ++q, n += 64) {
                uint4 v = *reinterpret_cast<const uint4*>(Wt + (size_t)n * 256 + kc * 64 + c8);
                *reinterpret_cast<uint4*>(w_s + n * 72 + c8) = v;
            }
        }
        __syncthreads();
        bf16x8 af[4][2], bfr[4][2];
        #pragma unroll
        for (int i = 0; i < 4; ++i)
            #pragma unroll
            for (int kk = 0; kk < 2; ++kk) {
                int m = wm * 64 + i * 16 + cl;
                int k = kk * 32 + (lane >> 4) * 8;
                af[i][kk] = *reinterpret_cast<const bf16x8*>(a_s + m * 72 + k);
            }
        #pragma unroll
        for (int j = 0; j < 4; ++j)
            #pragma unroll
            for (int kk = 0; kk < 2; ++kk) {
                int n = wn * 64 + j * 16 + cl;
                int k = kk * 32 + (lane >> 4) * 8;
                bfr[j][kk] = *reinterpret_cast<const bf16x8*>(w_s + n * 72 + k);
            }
        #pragma unroll
        for (int kk = 0; kk < 2; ++kk)
            #pragma unroll
            for (int i = 0; i < 4; ++i)
                #pragma unroll
                for (int j = 0; j < 4; ++j)
                    acc[i][j] = __builtin_amdgcn_mfma_f32_16x16x32_bf16(
                        af[i][kk], bfr[j][kk], acc[i][j], 0, 0, 0);
    }

    #pragma unroll
    for (int j = 0; j < 4; ++j) {
        int col = wn * 64 + j * 16 + cl;
        float bv = b_out[col];
        #pragma unroll
        for (int i = 0; i < 4; ++i) {
            int mb = wm * 64 + i * 16 + r4;
            #pragma unroll
            for (int r = 0; r < 4; ++r) {
                int row = m0 + mb + r;
                float sv = (row < M) ? src[(size_t)row * 256 + col] : 0.f;
                acc[i][j][r] += bv + sv;
            }
        }
    }
    #pragma unroll
    for (int i = 0; i < 4; ++i)
        #pragma unroll
        for (int r = 0; r < 4; ++r) {
            float s1 = 0.f, s2 = 0.f;
            #pragma unroll
            for (int j = 0; j < 4; ++j) { float t = acc[i][j][r]; s1 += t; s2 += t * t; }
            s1 += __shfl_xor(s1, 1); s2 += __shfl_xor(s2, 1);
            s1 += __shfl_xor(s1, 2); s2 += __shfl_xor(s2, 2);
            s1 += __shfl_xor(s1, 4); s2 += __shfl_xor(s2, 4);
            s1 += __shfl_xor(s1, 8); s2 += __shfl_xor(s2, 8);
            if (cl == 0) {
                int rr = wm * 64 + i * 16 + r4 + r;
                red[(rr * 4 + wn) * 2 + 0] = s1;
                red[(rr * 4 + wn) * 2 + 1] = s2;
            }
        }
    __syncthreads();
    if (tid < 128) {
        float s1 = red[tid * 8] + red[tid * 8 + 2] + red[tid * 8 + 4] + red[tid * 8 + 6];
        float s2 = red[tid * 8 + 1] + red[tid * 8 + 3] + red[tid * 8 + 5] + red[tid * 8 + 7];
        float mu = s1 * (1.f / 256.f);
        mr[tid * 2] = mu;
        mr[tid * 2 + 1] = rsqrtf(fmaxf(s2 * (1.f / 256.f) - mu * mu, 0.f) + 1e-5f);
    }
    __syncthreads();
    #pragma unroll
    for (int j = 0; j < 4; ++j) {
        int col = wn * 64 + j * 16 + cl;
        float gv = g1[col], bt = bt1[col];
        #pragma unroll
        for (int i = 0; i < 4; ++i) {
            int mb = wm * 64 + i * 16 + r4;
            #pragma unroll
            for (int r = 0; r < 4; ++r) {
                int rr = mb + r, row = m0 + rr;
                if (row < M)
                    X[(size_t)row * 256 + col] =
                        f2bf((acc[i][j][r] - mr[rr * 2]) * mr[rr * 2 + 1] * gv + bt);
            }
        }
    }
}

// ---------------------------------------------------------------------------
// Fused FFN + residual + LN2: out = LN(x + relu(x@W1+b1)@W2 + b2)
// ---------------------------------------------------------------------------
__global__ __launch_bounds__(512)
void k_ffn(const unsigned short* __restrict__ Xbf, const unsigned short* __restrict__ W1t,
           const float* __restrict__ B1, const unsigned short* __restrict__ W2t,
           const float* __restrict__ B2, const float* __restrict__ G2,
           const float* __restrict__ BT2, float* __restrict__ OUT, int M)
{
    __shared__ unsigned short x_s[128 * 264];
    __shared__ unsigned short h_s[128 * 264];
    __shared__ unsigned short w_s[256 * 40];
    __shared__ float red[128 * 8];
    __shared__ float mr[128 * 2];
    const int tid = threadIdx.x;
    const int m0 = blockIdx.x * 128;
    const int lane = tid & 63, wid = tid >> 6;
    const int wm = wid >> 2, wn = wid & 3;
    const int cl = lane & 15, r4 = (lane >> 4) * 4;

    #pragma unroll
    for (int it = 0; it < 8; ++it) {
        int id = tid + it * 512;
        int r = id >> 5, c8 = id & 31;
        uint4 v = make_uint4(0u, 0u, 0u, 0u);
        if (m0 + r < M)
            v = *reinterpret_cast<const uint4*>(Xbf + (size_t)(m0 + r) * 256 + c8 * 8);
        *reinterpret_cast<uint4*>(x_s + r * 264 + c8 * 8) = v;
    }

    f32x4 acc2[4][4] = {};

    for (int cc = 0; cc < 4; ++cc) {
        f32x4 acc1[4][4] = {};
        for (int ks = 0; ks < 8; ++ks) {
            __syncthreads();
            {
                int n = tid >> 1, cb = (tid & 1) * 2;
                #pragma unroll
                for (int e = 0; e < 2; ++e) {
                    uint4 v = *reinterpret_cast<const uint4*>(
                        W1t + (size_t)(cc * 256 + n) * 256 + ks * 32 + (cb + e) * 8);
                    *reinterpret_cast<uint4*>(w_s + n * 40 + (cb + e) * 8) = v;
                }
            }
            __syncthreads();
            bf16x8 bfr[4];
            #pragma unroll
            for (int j = 0; j < 4; ++j) {
                int n = wn * 64 + j * 16 + cl;
                bfr[j] = *reinterpret_cast<const bf16x8*>(w_s + n * 40 + (lane >> 4) * 8);
            }
            #pragma unroll
            for (int i = 0; i < 4; ++i) {
                int m = wm * 64 + i * 16 + cl;
                int k = ks * 32 + (lane >> 4) * 8;
                bf16x8 a = *reinterpret_cast<const bf16x8*>(x_s + m * 264 + k);
                #pragma unroll
                for (int j = 0; j < 4; ++j)
                    acc1[i][j] = __builtin_amdgcn_mfma_f32_16x16x32_bf16(
                        a, bfr[j], acc1[i][j], 0, 0, 0);
            }
        }
        #pragma unroll
        for (int j = 0; j < 4; ++j) {
            int kl = wn * 64 + j * 16 + cl;
            float bv = B1[cc * 256 + kl];
            #pragma unroll
            for (int i = 0; i < 4; ++i) {
                int m = wm * 64 + i * 16 + r4;
                #pragma unroll
                for (int r = 0; r < 4; ++r)
                    h_s[(m + r) * 264 + kl] = f2bf(fmaxf(acc1[i][j][r] + bv, 0.f));
            }
        }
        for (int ks = 0; ks < 8; ++ks) {
            __syncthreads();
            {
                int n = tid >> 1, cb = (tid & 1) * 2;
                #pragma unroll
                for (int e = 0; e < 2; ++e) {
                    uint4 v = *reinterpret_cast<const uint4*>(
                        W2t + (size_t)n * 1024 + cc * 256 + ks * 32 + (cb + e) * 8);
                    *reinterpret_cast<uint4*>(w_s + n * 40 + (cb + e) * 8) = v;
                }
            }
            __syncthreads();
            bf16x8 bfr[4];
            #pragma unroll
            for (int j = 0; j < 4; ++j) {
                int n = wn * 64 + j * 16 + cl;
                bfr[j] = *reinterpret_cast<const bf16x8*>(w_s + n * 40 + (lane >> 4) * 8);
            }
            #pragma unroll
            for (int i = 0; i < 4; ++i) {
                int m = wm * 64 + i * 16 + cl;
                int k = ks * 32 + (lane >> 4) * 8;
                bf16x8 a = *reinterpret_cast<const bf16x8*>(h_s + m * 264 + k);
                #pragma unroll
                for (int j = 0; j < 4; ++j)
                    acc2[i][j] = __builtin_amdgcn_mfma_f32_16x16x32_bf16(
                        a, bfr[j], acc2[i][j], 0, 0, 0);
            }
        }
    }

    #pragma unroll
    for (int j = 0; j < 4; ++j) {
        int col = wn * 64 + j * 16 + cl;
        float bv = B2[col];
        #pragma unroll
        for (int i = 0; i < 4; ++i) {
            int mb = wm * 64 + i * 16 + r4;
            #pragma unroll
            for (int r = 0; r < 4; ++r) {
                float xv = bf2f(x_s[(mb + r) * 264 + col]);
                acc2[i][j][r] += bv + xv;
            }
        }
    }
    #pragma unroll
    for (int i = 0; i < 4; ++i)
        #pragma unroll
        for (int r = 0; r < 4; ++r) {
            float s1 = 0.f, s2 = 0.f;
            #pragma unroll
            for (int j = 0; j < 4; ++j) { float t = acc2[i][j][r]; s1 += t; s2 += t * t; }
            s1 += __shfl_xor(s1, 1); s2 += __shfl_xor(s2, 1);
            s1 += __shfl_xor(s1, 2); s2 += __shfl_xor(s2, 2);
            s1 += __shfl_xor(s1, 4); s2 += __shfl_xor(s2, 4);
            s1 += __shfl_xor(s1, 8); s2 += __shfl_xor(s2, 8);
            if (cl == 0) {
                int rr = wm * 64 + i * 16 + r4 + r;
                red[(rr * 4 + wn) * 2 + 0] = s1;
                red[(rr * 4 + wn) * 2 + 1] = s2;
            }
        }
    __syncthreads();
    if (tid < 128) {
        float s1 = red[tid * 8] + red[tid * 8 + 2] + red[tid * 8 + 4] + red[tid * 8 + 6];
        float s2 = red[tid * 8 + 1] + red[tid * 8 + 3] + red[tid * 8 + 5] + red[tid * 8 + 7];
        float mu = s1 * (1.f / 256.f);
        mr[tid * 2] = mu;
        mr[tid * 2 + 1] = rsqrtf(fmaxf(s2 * (1.f / 256.f) - mu * mu, 0.f) + 1e-5f);
    }
    __syncthreads();
    #pragma unroll
    for (int j = 0; j < 4; ++j) {
        int col = wn * 64 + j * 16 + cl;
        float gv = G2[col], bt = BT2[col];
        #pragma unroll
        for (int i = 0; i < 4; ++i) {
            int mb = wm * 64 + i * 16 + r4;
            #pragma unroll
            for (int r = 0; r < 4; ++r) {
                int rr = mb + r, row = m0 + rr;
                if (row < M)
                    OUT[(size_t)row * 256 + col] =
                        (acc2[i][j][r] - mr[rr * 2]) * mr[rr * 2 + 1] * gv + bt;
            }
        }
    }
}

// ---------------------------------------------------------------------------
extern "C" void kernel_launch(void* const* d_in, const int* in_sizes, int n_in,
                              void* d_out, int out_size, void* d_ws, size_t ws_size,
                              hipStream_t stream) {
    const float* src    = (const float*)d_in[0];
    const float* ref    = (const float*)d_in[1];
    const int*   shapes = (const int*)d_in[2];
    const int*   lsi    = (const int*)d_in[3];
    const float* b_off  = (const float*)d_in[5];
    const float* b_att  = (const float*)d_in[7];
    const float* b_val  = (const float*)d_in[9];
    const float* b_out  = (const float*)d_in[11];
    const float* g1     = (const float*)d_in[12];
    const float* bt1    = (const float*)d_in[13];
    const float* b1     = (const float*)d_in[15];
    const float* b2     = (const float*)d_in[17];
    const float* g2     = (const float*)d_in[18];
    const float* bt2    = (const float*)d_in[19];
    const float* w_off  = (const float*)d_in[4];
    const float* w_att  = (const float*)d_in[6];
    const float* w_val  = (const float*)d_in[8];
    const float* w_out  = (const float*)d_in[10];
    const float* w1     = (const float*)d_in[14];
    const float* w2     = (const float*)d_in[16];

    const int M = in_sizes[0] / EMBED;  // B*nq = 49130
    const size_t M256 = (size_t)M * 256;

    unsigned short* w16     = (unsigned short*)d_ws;
    unsigned short* src_bf  = w16;
    unsigned short* value_bf = src_bf + M256;
    unsigned short* offr_bf = value_bf + M256;
    unsigned short* core_bf = offr_bf + M256;
    unsigned short* x_bf    = core_bf + M256;
    unsigned short* attw_bf = x_bf + M256;               // M*128
    unsigned short* wcat    = attw_bf + (size_t)M * 128; // 640*256
    unsigned short* woutt   = wcat + 163840;             // 256*256
    unsigned short* w1t     = woutt + 65536;             // 1024*256
    unsigned short* w2t     = w1t + 262144;              // 256*1024

    const int gb128 = (M + 127) / 128;
    const int gbS = (M + 3) / 4;

    k_cvt_src<<<4096, 256, 0, stream>>>(src, src_bf, M * 256);
    k_cvt_w<<<2944, 256, 0, stream>>>(w_val, w_off, w_att, w_out, w1, w2,
                                      wcat, woutt, w1t, w2t);
    k_proj<<<dim3(gb128, 3), 512, 0, stream>>>(src_bf, wcat, b_val, b_off, b_att,
                                               value_bf, offr_bf, attw_bf, M);
    k_sample<<<gbS, 256, 0, stream>>>(value_bf, offr_bf, attw_bf, ref, shapes, lsi,
                                      core_bf, M);
    k_oproj<<<gb128, 512, 0, stream>>>(core_bf, woutt, b_out, src, g1, bt1, x_bf, M);
    k_ffn<<<gb128, 512, 0, stream>>>(x_bf, w1t, b1, w2t, b2, g2, bt2,
                                     (float*)d_out, M);
}